// Round 1
// baseline (732.231 us; speedup 1.0000x reference)
//
#include <hip/hip_runtime.h>
#include <hip/hip_bf16.h>

// GCN 2-layer forward on MI355X.
// Inputs: x[N,512] f32, edge_index[2,E] int32, edge_weight[E] f32,
//         W1[512,16], b1[16], W2[16,10], b2[10]
// Outputs (concat): log_softmax(logits)[N,10], x1[N,16]

#define NF1 16   // hidden
#define NF2 10   // classes
#define FIN 512

// ---------- small init kernels ----------
__global__ __launch_bounds__(256) void init_deg_kernel(float* __restrict__ deg, int N) {
    int i = blockIdx.x * 256 + threadIdx.x;
    if (i < N) deg[i] = 1.0f;   // self-loop weight
}

__global__ __launch_bounds__(256) void deg_kernel(const int* __restrict__ col,
                                                  const float* __restrict__ ew,
                                                  float* __restrict__ deg, int E) {
    int e = blockIdx.x * 256 + threadIdx.x;
    if (e < E) unsafeAtomicAdd(&deg[col[e]], ew[e]);
}

__global__ __launch_bounds__(256) void dinv_kernel(float* __restrict__ deg, int N) {
    int i = blockIdx.x * 256 + threadIdx.x;
    if (i < N) {
        float d = deg[i];
        deg[i] = (d > 0.0f) ? rsqrtf(d) : 0.0f;
    }
}

__global__ __launch_bounds__(256) void init_logits_kernel(float* __restrict__ logits,
                                                          const float* __restrict__ b2, int n) {
    int i = blockIdx.x * 256 + threadIdx.x;
    if (i < n) logits[i] = b2[i % NF2];
}

__global__ __launch_bounds__(256) void init_x1_kernel(float* __restrict__ x1,
                                                      const float* __restrict__ b1, int n) {
    int i = blockIdx.x * 256 + threadIdx.x;
    if (i < n) x1[i] = b1[i & (NF1 - 1)];
}

// ---------- GEMM1: h = x @ W1   [N,512]@[512,16] ----------
// 16 threads per row (one per output feature); W1 transposed in LDS, pad 516
// so ds_read_b128 is 16B-aligned and ~conflict-free.
__global__ __launch_bounds__(256) void gemm1_kernel(const float* __restrict__ x,
                                                    const float* __restrict__ W1,
                                                    float* __restrict__ h, int N) {
    __shared__ float w1s[NF1 * 516];
    int tid = threadIdx.x;
    for (int idx = tid; idx < FIN * NF1; idx += 256) {
        int k = idx >> 4, f = idx & 15;
        w1s[f * 516 + k] = W1[idx];
    }
    __syncthreads();

    int r = tid >> 4, f = tid & 15;
    int row = blockIdx.x * 16 + r;
    if (row >= N) return;
    const float* xr = x + (size_t)row * FIN;
    const float* wf = w1s + f * 516;
    float acc = 0.0f;
#pragma unroll 4
    for (int k = 0; k < FIN; k += 4) {
        float4 xv = *reinterpret_cast<const float4*>(xr + k);
        float4 wv = *reinterpret_cast<const float4*>(wf + k);
        acc += xv.x * wv.x + xv.y * wv.y + xv.z * wv.z + xv.w * wv.w;
    }
    h[(size_t)row * NF1 + f] = acc;
}

// ---------- scatter layer 1: x1[col] += norm * h[row]  (16 feats) ----------
__global__ __launch_bounds__(256) void scatter1_kernel(const int* __restrict__ row,
                                                       const int* __restrict__ col,
                                                       const float* __restrict__ ew,
                                                       const float* __restrict__ dinv,
                                                       const float* __restrict__ h,
                                                       float* __restrict__ x1,
                                                       int E, int N) {
    int t = blockIdx.x * 256 + threadIdx.x;
    int total = (E + N) * NF1;
    if (t >= total) return;
    int e = t >> 4;
    int f = t & 15;
    int r, c; float w;
    if (e < E) { r = row[e]; c = col[e]; w = ew[e]; }
    else       { r = e - E; c = r;       w = 1.0f; }
    float nrm = dinv[r] * w * dinv[c];
    unsafeAtomicAdd(&x1[(size_t)c * NF1 + f], nrm * h[(size_t)r * NF1 + f]);
}

// ---------- GEMM2: hh = relu(x1) @ W2   [N,16]@[16,10] ----------
__global__ __launch_bounds__(256) void gemm2_kernel(const float* __restrict__ x1,
                                                    const float* __restrict__ W2,
                                                    float* __restrict__ hh, int N) {
    int j = blockIdx.x * 256 + threadIdx.x;
    if (j >= N) return;
    float xr[NF1];
#pragma unroll
    for (int f = 0; f < NF1; f++) xr[f] = fmaxf(x1[(size_t)j * NF1 + f], 0.0f);
#pragma unroll
    for (int c = 0; c < NF2; c++) {
        float acc = 0.0f;
#pragma unroll
        for (int f = 0; f < NF1; f++) acc += xr[f] * W2[f * NF2 + c];
        hh[(size_t)j * NF2 + c] = acc;
    }
}

// ---------- scatter layer 2: logits[col] += norm * hh[row]  (10 feats) ----------
__global__ __launch_bounds__(256) void scatter2_kernel(const int* __restrict__ row,
                                                       const int* __restrict__ col,
                                                       const float* __restrict__ ew,
                                                       const float* __restrict__ dinv,
                                                       const float* __restrict__ hh,
                                                       float* __restrict__ logits,
                                                       int E, int N) {
    int t = blockIdx.x * 256 + threadIdx.x;
    int total = (E + N) * NF2;
    if (t >= total) return;
    int e = t / NF2;
    int c10 = t - e * NF2;
    int r, c; float w;
    if (e < E) { r = row[e]; c = col[e]; w = ew[e]; }
    else       { r = e - E; c = r;       w = 1.0f; }
    float nrm = dinv[r] * w * dinv[c];
    unsafeAtomicAdd(&logits[(size_t)c * NF2 + c10], nrm * hh[(size_t)r * NF2 + c10]);
}

// ---------- log_softmax rows of 10, in place ----------
__global__ __launch_bounds__(256) void lsm_kernel(float* __restrict__ logits, int N) {
    int j = blockIdx.x * 256 + threadIdx.x;
    if (j >= N) return;
    float v[NF2];
#pragma unroll
    for (int c = 0; c < NF2; c++) v[c] = logits[(size_t)j * NF2 + c];
    float m = v[0];
#pragma unroll
    for (int c = 1; c < NF2; c++) m = fmaxf(m, v[c]);
    float s = 0.0f;
#pragma unroll
    for (int c = 0; c < NF2; c++) s += expf(v[c] - m);
    float ls = logf(s);
#pragma unroll
    for (int c = 0; c < NF2; c++) logits[(size_t)j * NF2 + c] = v[c] - m - ls;
}

extern "C" void kernel_launch(void* const* d_in, const int* in_sizes, int n_in,
                              void* d_out, int out_size, void* d_ws, size_t ws_size,
                              hipStream_t stream) {
    const float* x  = (const float*)d_in[0];
    const int*   ei = (const int*)d_in[1];
    const float* ew = (const float*)d_in[2];
    const float* W1 = (const float*)d_in[3];
    const float* b1 = (const float*)d_in[4];
    const float* W2 = (const float*)d_in[5];
    const float* b2 = (const float*)d_in[6];

    const int E = in_sizes[2];           // 3,200,000
    const int N = in_sizes[0] / FIN;     // 100,000
    const int* row = ei;
    const int* col = ei + E;

    float* out    = (float*)d_out;
    float* logits = out;                        // [N,10]
    float* x1     = out + (size_t)N * NF2;      // [N,16]

    char* ws = (char*)d_ws;
    size_t off = 0;
    float* h  = (float*)(ws + off); off += ((size_t)N * NF1 * 4 + 255) / 256 * 256;
    float* hh = (float*)(ws + off); off += ((size_t)N * NF2 * 4 + 255) / 256 * 256;
    float* deg = (float*)(ws + off); off += ((size_t)N * 4 + 255) / 256 * 256;
    (void)ws_size; (void)n_in; (void)out_size;

    dim3 blk(256);
    int gN = (N + 255) / 256;

    // degree (self-loops pre-counted as 1.0) -> dinv in place
    init_deg_kernel<<<gN, blk, 0, stream>>>(deg, N);
    deg_kernel<<<(E + 255) / 256, blk, 0, stream>>>(col, ew, deg, E);
    dinv_kernel<<<gN, blk, 0, stream>>>(deg, N);

    // init scatter targets with biases (d_out is poisoned each timing run)
    init_logits_kernel<<<((N * NF2) + 255) / 256, blk, 0, stream>>>(logits, b2, N * NF2);
    init_x1_kernel<<<((N * NF1) + 255) / 256, blk, 0, stream>>>(x1, b1, N * NF1);

    // layer 1
    gemm1_kernel<<<N / 16, blk, 0, stream>>>(x, W1, h, N);
    scatter1_kernel<<<(((E + N) * NF1) + 255) / 256, blk, 0, stream>>>(row, col, ew, deg, h, x1, E, N);

    // layer 2
    gemm2_kernel<<<gN, blk, 0, stream>>>(x1, W2, hh, N);
    scatter2_kernel<<<(((E + N) * NF2) + 255) / 256, blk, 0, stream>>>(row, col, ew, deg, hh, logits, E, N);

    // log-softmax in place on logits
    lsm_kernel<<<gN, blk, 0, stream>>>(logits, N);
}